// Round 8
// baseline (2431.623 us; speedup 1.0000x reference)
//
#include <hip/hip_runtime.h>

typedef unsigned short u16;
typedef unsigned int u32;

#define NN 20000
#define NE 320000

// ---------------- workspace layout (bytes) ----------------
#define WS_FLAG  0         // 1 i32: 1 = inputs are bf16, 0 = inputs are f32
#define WS_H     256       // 640 f32   H[z][c]
#define WS_U1    3072      // 36  f32
#define WS_U2    3328      // 180 f32   U2sym[45][4]
#define WS_U3    4096      // 660 f32   U3sym[165][4]
#define WS_DEG   7168      // 20000 i32
#define WS_CUR   87168     // 20000 i32 (contiguous after DEG; one memset covers both)
#define WS_OFF   167168    // 20000 i32
#define WS_BSUM  247168    // 79 i32
#define WS_BOFF  247552    // 79 i32
#define WS_ELIST 248064    // 320000 i32
#define WS_POSF  1528064   // 20000 float4

__device__ __forceinline__ float bf2f(u16 u){ return __uint_as_float(((u32)u) << 16); }
__device__ __forceinline__ u16 f2bf(float f){
  u32 u = __float_as_uint(f);
  u32 r = (u + 0x7fffu + ((u >> 16) & 1u)) >> 16;
  return (u16)r;
}
__device__ __forceinline__ float bflo(u32 d){ return __uint_as_float(d << 16); }
__device__ __forceinline__ float bfhi(u32 d){ return __uint_as_float(d & 0xffff0000u); }
__device__ __forceinline__ float silu_f(float v){ return v / (1.0f + __expf(-v)); }

// dtype-agnostic float load: bf=1 -> buffer holds bf16 u16, bf=0 -> f32
__device__ __forceinline__ float ldf(const void* p, int i, int bf){
  return bf ? bf2f(((const u16*)p)[i]) : ((const float*)p)[i];
}

// Wave-synchronous LDS exchange fence (proven R4-R7): wave64 lanes are
// lockstep; wave_barrier pins scheduling, waitcnt drains the DS queue, memory
// clobber stops reordering/forwarding. No s_barrier — waves stay decoupled.
#define WAVE_SYNC() do { \
  __builtin_amdgcn_wave_barrier(); \
  asm volatile("s_waitcnt lgkmcnt(0)" ::: "memory"); \
  __builtin_amdgcn_wave_barrier(); \
} while (0)

// ---------------- dtype sniffer ----------------
extern "C" __global__ __launch_bounds__(256)
void k_sniff(const u32* __restrict__ wu, int* __restrict__ flag)
{
  __shared__ int s[256];
  int tid = threadIdx.x;
  u32 w = wu[tid];
  u32 e = (w >> 7) & 0xFFu;   // exponent field of the low-half bf16
  s[tid] = (e >= 0x60u && e <= 0x86u) ? 1 : 0;
  __syncthreads();
  for (int d = 128; d > 0; d >>= 1){
    if (tid < d) s[tid] += s[tid + d];
    __syncthreads();
  }
  if (tid == 0) flag[0] = (s[0] > 148) ? 1 : 0;
}

// ---------------- prep: H table + symmetrized U tables ----------------
extern "C" __global__ __launch_bounds__(256)
void k_prep(const void* __restrict__ We, const void* __restrict__ Wu,
            const void* __restrict__ U3, const void* __restrict__ U2, const void* __restrict__ U1,
            const int* __restrict__ flagp,
            float* __restrict__ Hws, float* __restrict__ U3ws,
            float* __restrict__ U2ws, float* __restrict__ U1ws)
{
  int bf = flagp[0];
  int tid = threadIdx.x;
  for (int t = tid; t < 640; t += 256){
    int z = t >> 6, c = t & 63;
    float s = 0.f;
    for (int k = 0; k < 64; ++k) s += ldf(We, z*64 + k, bf) * ldf(Wu, k*64 + c, bf);
    Hws[t] = s * 0.0395284708f;   // 1/sqrt(Z*C) = 1/sqrt(640)
  }
  for (int t = tid; t < 36; t += 256) U1ws[t] = ldf(U1, t, bf);
  for (int t = tid; t < 45; t += 256){
    int j = 0, rem = t;
    for (;;){ int cnt = 9 - j; if (rem < cnt) break; rem -= cnt; ++j; }
    int k = j + rem;
    for (int p = 0; p < 4; ++p){
      float v = ldf(U2, (j*9 + k)*4 + p, bf);
      if (k > j) v += ldf(U2, (k*9 + j)*4 + p, bf);
      U2ws[t*4 + p] = v;
    }
  }
  for (int t = tid; t < 165; t += 256){
    int i = 0, rem = t;
    for (;;){ int m = 9 - i; int cnt = m*(m+1)/2; if (rem < cnt) break; rem -= cnt; ++i; }
    int j = i;
    for (;;){ int cnt = 9 - j; if (rem < cnt) break; rem -= cnt; ++j; }
    int k = j + rem;
    int pm[6][3] = {{i,j,k},{i,k,j},{j,i,k},{j,k,i},{k,i,j},{k,j,i}};
    float acc[4] = {0,0,0,0};
    for (int m = 0; m < 6; ++m){
      bool dup = false;
      for (int mm = 0; mm < m; ++mm)
        if (pm[mm][0]==pm[m][0] && pm[mm][1]==pm[m][1] && pm[mm][2]==pm[m][2]) dup = true;
      if (!dup){
        int base = ((pm[m][0]*9 + pm[m][1])*9 + pm[m][2])*4;
        for (int p = 0; p < 4; ++p) acc[p] += ldf(U3, base + p, bf);
      }
    }
    for (int p = 0; p < 4; ++p) U3ws[t*4 + p] = acc[p];
  }
}

// ---------------- positions -> float4 ----------------
extern "C" __global__ __launch_bounds__(256)
void k_pos(const void* __restrict__ pos, const int* __restrict__ flagp, float4* __restrict__ posf)
{
  int bf = flagp[0];
  int i = blockIdx.x*256 + threadIdx.x;
  if (i < NN){
    float4 v;
    v.x = ldf(pos, 3*i+0, bf); v.y = ldf(pos, 3*i+1, bf); v.z = ldf(pos, 3*i+2, bf); v.w = 0.f;
    posf[i] = v;
  }
}

// ---------------- CSR build ----------------
extern "C" __global__ __launch_bounds__(256)
void k_deg(const int* __restrict__ eidx, int* __restrict__ deg)
{
  int e = blockIdx.x*256 + threadIdx.x;
  if (e < NE) atomicAdd(&deg[eidx[NE + e]], 1);
}

extern "C" __global__ __launch_bounds__(256)
void k_scan_a(const int* __restrict__ deg, int* __restrict__ bsum)
{
  __shared__ int s[256];
  int tid = threadIdx.x;
  int i = blockIdx.x*256 + tid;
  s[tid] = (i < NN) ? deg[i] : 0;
  __syncthreads();
  for (int d = 128; d > 0; d >>= 1){
    if (tid < d) s[tid] += s[tid + d];
    __syncthreads();
  }
  if (tid == 0) bsum[blockIdx.x] = s[0];
}

extern "C" __global__ __launch_bounds__(128)
void k_scan_b(const int* __restrict__ bsum, int* __restrict__ boff)
{
  __shared__ int s[128];
  int tid = threadIdx.x;
  int v = (tid < 79) ? bsum[tid] : 0;
  s[tid] = v;
  __syncthreads();
  for (int d = 1; d < 128; d <<= 1){
    int t = (tid >= d) ? s[tid - d] : 0;
    __syncthreads();
    s[tid] += t;
    __syncthreads();
  }
  if (tid < 79) boff[tid] = s[tid] - v;
}

extern "C" __global__ __launch_bounds__(256)
void k_scan_c(const int* __restrict__ deg, const int* __restrict__ boff, int* __restrict__ offs)
{
  __shared__ int s[256];
  int tid = threadIdx.x;
  int i = blockIdx.x*256 + tid;
  int v = (i < NN) ? deg[i] : 0;
  s[tid] = v;
  __syncthreads();
  for (int d = 1; d < 256; d <<= 1){
    int t = (tid >= d) ? s[tid - d] : 0;
    __syncthreads();
    s[tid] += t;
    __syncthreads();
  }
  if (i < NN) offs[i] = boff[blockIdx.x] + s[tid] - v;
}

extern "C" __global__ __launch_bounds__(256)
void k_scatter(const int* __restrict__ eidx, const int* __restrict__ offs,
               int* __restrict__ cur, int* __restrict__ elist)
{
  int e = blockIdx.x*256 + threadIdx.x;
  if (e < NE){
    int r = eidx[NE + e];
    int p = atomicAdd(&cur[r], 1);
    elist[offs[r] + p] = e;
  }
}

// ---------------- edge geometry ----------------
__device__ __forceinline__ void edge_geom(float4 pr, float4 ps, float* ef, float* Y)
{
  float vx = pr.x - ps.x, vy = pr.y - ps.y, vz = pr.z - ps.z;
  float r2 = vx*vx + vy*vy + vz*vz + 1e-12f;
  float rinv = rsqrtf(r2);
  float r = r2 * rinv;
  float ux = vx*rinv, uy = vy*rinv, uz = vz*rinv;
  const float s3 = 1.7320508076f, s5 = 2.2360679775f, s15 = 3.8729833462f;
  Y[0] = 1.0f;
  Y[1] = s3*ux; Y[2] = s3*uy; Y[3] = s3*uz;
  Y[4] = s15*ux*uy; Y[5] = s15*uy*uz;
  Y[6] = 0.5f*s5*(3.0f*uz*uz - 1.0f);
  Y[7] = s15*ux*uz;
  Y[8] = 0.5f*s15*(ux*ux - uy*uy);
  float u = r * 0.2f; u = fminf(u, 1.0f);
  float u2 = u*u, u4 = u2*u2, u6 = u4*u2, u7 = u6*u, u8 = u7*u;
  float fc = 1.0f - 28.0f*u6 + 48.0f*u7 - 21.0f*u8;
  float c0 = 0.63245553203f * fc * rinv;     // sqrt(2/RMAX)*fcut/r
  float w = 0.62831853072f * r;              // pi*r/RMAX
  #pragma unroll
  for (int k = 0; k < 8; ++k) ef[k] = c0 * __sinf(w * (float)(k + 1));
}

// ---------------- main fused kernel ----------------
// 512-thread blocks (8 waves) sharing ONE weight copy -> LDS ~78 KB/block,
// 2 blocks/CU = 16 waves/CU (the VGPR-84 residency cap; R7's 256-thread
// blocks fell to 2 blocks = 8 waves via the LDS granule cliff). W_out is
// staged f32 up-front in its own region, so there are ZERO block-wide
// barriers after init — waves fully decoupled. Keeps R7's per-wave wins:
// batched parallel gather + 3-slot pipeline (3 syncs/edge).
extern "C" __global__ __launch_bounds__(512, 4)
void k_main(const int* __restrict__ atom, const int* __restrict__ eidx,
            const void* __restrict__ w1g, const void* __restrict__ w2g,
            const void* __restrict__ w3g, const void* __restrict__ w4g,
            const void* __restrict__ Wc3, const void* __restrict__ Wc2, const void* __restrict__ Wc1,
            const void* __restrict__ Woutg,
            const float* __restrict__ Hws, const float* __restrict__ U3ws,
            const float* __restrict__ U2ws, const float* __restrict__ U1ws,
            const float4* __restrict__ posf,
            const int* __restrict__ deg, const int* __restrict__ offs, const int* __restrict__ elist,
            const int* __restrict__ flagp, void* __restrict__ outp)
{
  __shared__ __align__(16) u16  w2s[8][64][8];     // [k8][j][k%8]
  __shared__ __align__(16) u16  w3s[8][64][8];
  __shared__ __align__(16) u16  w4s[8][3][64][8];  // [k8][l][c][k%8]
  __shared__ __align__(16) float wos[4096];        // W_out f32, staged once
  __shared__ __align__(16) float Hs[10][64];
  __shared__ __align__(16) float U3t[165][4];
  __shared__ __align__(16) float U2t[45][4];
  __shared__ __align__(16) float U1t[9][4];
  __shared__ __align__(16) float fbuf[8][3][64];   // 3-slot activation pipeline per wave
  __shared__ __align__(16) float4 ebuf[8][64];     // per-wave edge cache: xyz=pos, w=atom(z)

  int bf = flagp[0];
  int tid = threadIdx.x;
  for (int t = tid; t < 4096; t += 512){
    int k = t >> 6, j = t & 63;
    u16 v2 = bf ? ((const u16*)w2g)[t] : f2bf(((const float*)w2g)[t]);
    u16 v3 = bf ? ((const u16*)w3g)[t] : f2bf(((const float*)w3g)[t]);
    w2s[k>>3][j][k&7] = v2;
    w3s[k>>3][j][k&7] = v3;
    wos[t] = ldf(Woutg, t, bf);
  }
  for (int t = tid; t < 12288; t += 512){
    int k = t / 192, col = t % 192;
    u16 v4 = bf ? ((const u16*)w4g)[t] : f2bf(((const float*)w4g)[t]);
    w4s[k>>3][col>>6][col&63][k&7] = v4;
  }
  for (int t = tid; t < 640; t += 512) ((float*)Hs)[t]  = Hws[t];
  for (int t = tid; t < 660; t += 512) ((float*)U3t)[t] = U3ws[t];
  for (int t = tid; t < 180; t += 512) ((float*)U2t)[t] = U2ws[t];
  for (int t = tid; t < 36;  t += 512) ((float*)U1t)[t] = U1ws[t];
  __syncthreads();                                  // the ONLY block-wide barrier

  int wv = tid >> 6;
  int lane = tid & 63;
  int n = blockIdx.x * 8 + wv;
  int start = offs[n];
  int cnt = deg[n];
  float4 pr = posf[n];

  // L1 weights live in registers (saves 8 LDS reads per edge)
  float w1r[8];
  #pragma unroll
  for (int k = 0; k < 8; ++k) w1r[k] = ldf(w1g, k*64 + lane, bf);

  const float4* fbS0 = (const float4*)&fbuf[wv][0][0];
  const float4* fbS1 = (const float4*)&fbuf[wv][1][0];
  const float4* fbS2 = (const float4*)&fbuf[wv][2][0];

  float X[9];
  #pragma unroll
  for (int m = 0; m < 9; ++m) X[m] = 0.f;

  // Outer: 64-edge batches (avg degree 16 -> usually one batch per node).
  #pragma unroll 1
  for (int base = 0; base < cnt; base += 64){
    int nb = min(cnt - base, 64);

    // ---- batched parallel gather: lane j resolves edge base+j's chain ----
    if (lane < nb){
      int e = elist[start + base + lane];   // coalesced
      int s = eidx[e];                      // parallel gather
      float4 p = posf[s];                   // parallel gather
      p.w = __int_as_float(atom[s]);        // parallel gather
      ebuf[wv][lane] = p;
    }
    WAVE_SYNC();

    // ---- per-edge MLP loop; edge data via broadcast LDS reads ----
    for (int i = 0; i < nb; ++i){
      float4 q = ebuf[wv][i];
      int z = __float_as_int(q.w);

      float ef[8], Y[9];
      edge_geom(pr, q, ef, Y);

      // ---- L1: 8 -> 64 (weights in regs) -> S0 ----
      float a = 0.f;
      #pragma unroll
      for (int k = 0; k < 8; ++k) a += ef[k] * w1r[k];
      a = silu_f(a);
      fbuf[wv][0][lane] = a;
      WAVE_SYNC();

      // ---- L2: 64 -> 64, S0 -> S1 ----
      {
        float p0 = 0.f, p1 = 0.f;
        #pragma unroll
        for (int k8 = 0; k8 < 8; ++k8){
          uint4 w = *(const uint4*)&w2s[k8][lane][0];
          float4 f0 = fbS0[2*k8], f1 = fbS0[2*k8+1];
          p0 += bflo(w.x)*f0.x + bfhi(w.x)*f0.y + bflo(w.y)*f0.z + bfhi(w.y)*f0.w;
          p1 += bflo(w.z)*f1.x + bfhi(w.z)*f1.y + bflo(w.w)*f1.z + bfhi(w.w)*f1.w;
        }
        a = silu_f(p0 + p1);
      }
      fbuf[wv][1][lane] = a;
      WAVE_SYNC();

      // ---- L3: 64 -> 64, S1 -> S2 ----
      {
        float p0 = 0.f, p1 = 0.f;
        #pragma unroll
        for (int k8 = 0; k8 < 8; ++k8){
          uint4 w = *(const uint4*)&w3s[k8][lane][0];
          float4 f0 = fbS1[2*k8], f1 = fbS1[2*k8+1];
          p0 += bflo(w.x)*f0.x + bfhi(w.x)*f0.y + bflo(w.y)*f0.z + bfhi(w.y)*f0.w;
          p1 += bflo(w.z)*f1.x + bfhi(w.z)*f1.y + bflo(w.w)*f1.z + bfhi(w.w)*f1.w;
        }
        a = silu_f(p0 + p1);
      }
      fbuf[wv][2][lane] = a;
      WAVE_SYNC();

      // ---- L4: 64 -> 192 (tpw[l][lane]), reads S2; no trailing sync needed:
      // next L1 writes S0 (readers drained 2 syncs ago); next-edge syncs
      // drain these S2 reads before S2 is rewritten. ----
      float t0 = 0.f, t1 = 0.f, t2 = 0.f;
      #pragma unroll
      for (int k8 = 0; k8 < 8; ++k8){
        float4 f0 = fbS2[2*k8], f1 = fbS2[2*k8+1];
        uint4 qa = *(const uint4*)&w4s[k8][0][lane][0];
        t0 += bflo(qa.x)*f0.x + bfhi(qa.x)*f0.y + bflo(qa.y)*f0.z + bfhi(qa.y)*f0.w
            + bflo(qa.z)*f1.x + bfhi(qa.z)*f1.y + bflo(qa.w)*f1.z + bfhi(qa.w)*f1.w;
        uint4 qb = *(const uint4*)&w4s[k8][1][lane][0];
        t1 += bflo(qb.x)*f0.x + bfhi(qb.x)*f0.y + bflo(qb.y)*f0.z + bfhi(qb.y)*f0.w
            + bflo(qb.z)*f1.x + bfhi(qb.z)*f1.y + bflo(qb.w)*f1.z + bfhi(qb.w)*f1.w;
        uint4 qc = *(const uint4*)&w4s[k8][2][lane][0];
        t2 += bflo(qc.x)*f0.x + bfhi(qc.x)*f0.y + bflo(qc.y)*f0.z + bfhi(qc.y)*f0.w
            + bflo(qc.z)*f1.x + bfhi(qc.z)*f1.y + bflo(qc.w)*f1.z + bfhi(qc.w)*f1.w;
      }

      // ---- accumulate messages ----
      float h = Hs[z][lane];
      float q0 = h*t0, q1 = h*t1, q2 = h*t2;
      X[0] += q0*Y[0];
      X[1] += q1*Y[1]; X[2] += q1*Y[2]; X[3] += q1*Y[3];
      X[4] += q2*Y[4]; X[5] += q2*Y[5]; X[6] += q2*Y[6];
      X[7] += q2*Y[7]; X[8] += q2*Y[8];
    }
  }

  #pragma unroll
  for (int m = 0; m < 9; ++m) X[m] *= 0.0625f;   // / AVG

  // ---- contraction (rolled to keep VGPRs low) ----
  float s1a[4] = {0,0,0,0}, s2a[4] = {0,0,0,0}, s3a[4] = {0,0,0,0};
  #pragma unroll
  for (int j = 0; j < 9; ++j){
    float4 u = *(const float4*)&U1t[j][0];
    s1a[0] += u.x*X[j]; s1a[1] += u.y*X[j]; s1a[2] += u.z*X[j]; s1a[3] += u.w*X[j];
  }
  {
    int t2i = 0;
    #pragma unroll 1
    for (int j = 0; j < 9; ++j){
      #pragma unroll 1
      for (int k = j; k < 9; ++k){
        float m = X[j]*X[k];
        float4 u = *(const float4*)&U2t[t2i][0]; ++t2i;
        s2a[0] += u.x*m; s2a[1] += u.y*m; s2a[2] += u.z*m; s2a[3] += u.w*m;
      }
    }
  }
  {
    int t3i = 0;
    #pragma unroll 1
    for (int i = 0; i < 9; ++i){
      #pragma unroll 1
      for (int j = i; j < 9; ++j){
        float mij = X[i]*X[j];
        #pragma unroll 1
        for (int k = j; k < 9; ++k){
          float m = mij*X[k];
          float4 u = *(const float4*)&U3t[t3i][0]; ++t3i;
          s3a[0] += u.x*m; s3a[1] += u.y*m; s3a[2] += u.z*m; s3a[3] += u.w*m;
        }
      }
    }
  }

  int zn = atom[n];
  float outval = 0.f;
  #pragma unroll
  for (int p = 0; p < 4; ++p){
    int base = (zn*4 + p)*64 + lane;
    outval += ldf(Wc1, base, bf)*s1a[p] + ldf(Wc2, base, bf)*s2a[p] + ldf(Wc3, base, bf)*s3a[p];
  }

  // ---- fused final matmul (wos pre-staged; per-wave, no barrier) ----
  fbuf[wv][0][lane] = outval;
  WAVE_SYNC();
  float acc = 0.f;
  #pragma unroll
  for (int cb = 0; cb < 16; ++cb){
    float4 p = fbS0[cb];
    acc += p.x*wos[(4*cb+0)*64 + lane] + p.y*wos[(4*cb+1)*64 + lane]
         + p.z*wos[(4*cb+2)*64 + lane] + p.w*wos[(4*cb+3)*64 + lane];
  }
  acc *= 0.125f;
  if (bf) ((u16*)outp)[n*64 + lane] = f2bf(acc);
  else    ((float*)outp)[n*64 + lane] = acc;
}

// ---------------- host ----------------
extern "C" void kernel_launch(void* const* d_in, const int* in_sizes, int n_in,
                              void* d_out, int out_size, void* d_ws, size_t ws_size,
                              hipStream_t stream)
{
  const void* pos  = d_in[0];
  const int* atom  = (const int*)d_in[1];
  const int* eidx  = (const int*)d_in[2];
  const void* We   = d_in[3];
  const void* Wu   = d_in[4];
  const void* w1g  = d_in[5];
  const void* w2g  = d_in[6];
  const void* w3g  = d_in[7];
  const void* w4g  = d_in[8];
  const void* U3   = d_in[9];
  const void* U2   = d_in[10];
  const void* U1   = d_in[11];
  const void* Wc3  = d_in[12];
  const void* Wc2  = d_in[13];
  const void* Wc1  = d_in[14];
  const void* Wout = d_in[15];

  char* ws = (char*)d_ws;
  int*    flag  = (int*)(ws + WS_FLAG);
  float*  Hws   = (float*)(ws + WS_H);
  float*  U1ws  = (float*)(ws + WS_U1);
  float*  U2ws  = (float*)(ws + WS_U2);
  float*  U3ws  = (float*)(ws + WS_U3);
  int*    deg   = (int*)(ws + WS_DEG);
  int*    cur   = (int*)(ws + WS_CUR);
  int*    offs  = (int*)(ws + WS_OFF);
  int*    bsum  = (int*)(ws + WS_BSUM);
  int*    boff  = (int*)(ws + WS_BOFF);
  int*    elist = (int*)(ws + WS_ELIST);
  float4* posf  = (float4*)(ws + WS_POSF);

  (void)hipMemsetAsync(ws + WS_DEG, 0, 160000, stream);   // deg + cur

  k_sniff<<<1, 256, 0, stream>>>((const u32*)Wu, flag);
  k_prep<<<1, 256, 0, stream>>>(We, Wu, U3, U2, U1, flag, Hws, U3ws, U2ws, U1ws);
  k_pos<<<79, 256, 0, stream>>>(pos, flag, posf);
  k_deg<<<1250, 256, 0, stream>>>(eidx, deg);
  k_scan_a<<<79, 256, 0, stream>>>(deg, bsum);
  k_scan_b<<<1, 128, 0, stream>>>(bsum, boff);
  k_scan_c<<<79, 256, 0, stream>>>(deg, boff, offs);
  k_scatter<<<1250, 256, 0, stream>>>(eidx, offs, cur, elist);
  k_main<<<2500, 512, 0, stream>>>(atom, eidx, w1g, w2g, w3g, w4g, Wc3, Wc2, Wc1, Wout,
                                   Hws, U3ws, U2ws, U1ws, posf, deg, offs, elist,
                                   flag, d_out);
}

// Round 9
// 1394.456 us; speedup vs baseline: 1.7438x; 1.7438x over previous
//
#include <hip/hip_runtime.h>

typedef unsigned short u16;
typedef unsigned int u32;

#define NN 20000
#define NE 320000

// ---------------- workspace layout (bytes) ----------------
#define WS_FLAG  0         // 1 i32: 1 = inputs are bf16, 0 = inputs are f32
#define WS_H     256       // 640 f32   H[z][c]
#define WS_U1    3072      // 36  f32
#define WS_U2    3328      // 180 f32   U2sym[45][4]
#define WS_U3    4096      // 660 f32   U3sym[165][4]
#define WS_DEG   7168      // 20000 i32
#define WS_CUR   87168     // 20000 i32 (contiguous after DEG; one memset covers both)
#define WS_OFF   167168    // 20000 i32
#define WS_BSUM  247168    // 79 i32
#define WS_BOFF  247552    // 79 i32
#define WS_ELIST 248064    // 320000 i32
#define WS_POSF  1528064   // 20000 float4

__device__ __forceinline__ float bf2f(u16 u){ return __uint_as_float(((u32)u) << 16); }
__device__ __forceinline__ u16 f2bf(float f){
  u32 u = __float_as_uint(f);
  u32 r = (u + 0x7fffu + ((u >> 16) & 1u)) >> 16;
  return (u16)r;
}
__device__ __forceinline__ float bflo(u32 d){ return __uint_as_float(d << 16); }
__device__ __forceinline__ float bfhi(u32 d){ return __uint_as_float(d & 0xffff0000u); }
__device__ __forceinline__ float silu_f(float v){ return v / (1.0f + __expf(-v)); }

// dtype-agnostic float load: bf=1 -> buffer holds bf16 u16, bf=0 -> f32
__device__ __forceinline__ float ldf(const void* p, int i, int bf){
  return bf ? bf2f(((const u16*)p)[i]) : ((const float*)p)[i];
}

// Wave-synchronous LDS exchange fence (proven R4-R8): wave64 lanes are
// lockstep; wave_barrier pins scheduling, waitcnt drains the DS queue, memory
// clobber stops reordering/forwarding. No s_barrier — waves stay decoupled.
#define WAVE_SYNC() do { \
  __builtin_amdgcn_wave_barrier(); \
  asm volatile("s_waitcnt lgkmcnt(0)" ::: "memory"); \
  __builtin_amdgcn_wave_barrier(); \
} while (0)

// ---------------- dtype sniffer ----------------
extern "C" __global__ __launch_bounds__(256)
void k_sniff(const u32* __restrict__ wu, int* __restrict__ flag)
{
  __shared__ int s[256];
  int tid = threadIdx.x;
  u32 w = wu[tid];
  u32 e = (w >> 7) & 0xFFu;   // exponent field of the low-half bf16
  s[tid] = (e >= 0x60u && e <= 0x86u) ? 1 : 0;
  __syncthreads();
  for (int d = 128; d > 0; d >>= 1){
    if (tid < d) s[tid] += s[tid + d];
    __syncthreads();
  }
  if (tid == 0) flag[0] = (s[0] > 148) ? 1 : 0;
}

// ---------------- prep: H table + symmetrized U tables ----------------
extern "C" __global__ __launch_bounds__(256)
void k_prep(const void* __restrict__ We, const void* __restrict__ Wu,
            const void* __restrict__ U3, const void* __restrict__ U2, const void* __restrict__ U1,
            const int* __restrict__ flagp,
            float* __restrict__ Hws, float* __restrict__ U3ws,
            float* __restrict__ U2ws, float* __restrict__ U1ws)
{
  int bf = flagp[0];
  int tid = threadIdx.x;
  for (int t = tid; t < 640; t += 256){
    int z = t >> 6, c = t & 63;
    float s = 0.f;
    for (int k = 0; k < 64; ++k) s += ldf(We, z*64 + k, bf) * ldf(Wu, k*64 + c, bf);
    Hws[t] = s * 0.0395284708f;   // 1/sqrt(Z*C) = 1/sqrt(640)
  }
  for (int t = tid; t < 36; t += 256) U1ws[t] = ldf(U1, t, bf);
  for (int t = tid; t < 45; t += 256){
    int j = 0, rem = t;
    for (;;){ int cnt = 9 - j; if (rem < cnt) break; rem -= cnt; ++j; }
    int k = j + rem;
    for (int p = 0; p < 4; ++p){
      float v = ldf(U2, (j*9 + k)*4 + p, bf);
      if (k > j) v += ldf(U2, (k*9 + j)*4 + p, bf);
      U2ws[t*4 + p] = v;
    }
  }
  for (int t = tid; t < 165; t += 256){
    int i = 0, rem = t;
    for (;;){ int m = 9 - i; int cnt = m*(m+1)/2; if (rem < cnt) break; rem -= cnt; ++i; }
    int j = i;
    for (;;){ int cnt = 9 - j; if (rem < cnt) break; rem -= cnt; ++j; }
    int k = j + rem;
    int pm[6][3] = {{i,j,k},{i,k,j},{j,i,k},{j,k,i},{k,i,j},{k,j,i}};
    float acc[4] = {0,0,0,0};
    for (int m = 0; m < 6; ++m){
      bool dup = false;
      for (int mm = 0; mm < m; ++mm)
        if (pm[mm][0]==pm[m][0] && pm[mm][1]==pm[m][1] && pm[mm][2]==pm[m][2]) dup = true;
      if (!dup){
        int base = ((pm[m][0]*9 + pm[m][1])*9 + pm[m][2])*4;
        for (int p = 0; p < 4; ++p) acc[p] += ldf(U3, base + p, bf);
      }
    }
    for (int p = 0; p < 4; ++p) U3ws[t*4 + p] = acc[p];
  }
}

// ---------------- positions -> float4 ----------------
extern "C" __global__ __launch_bounds__(256)
void k_pos(const void* __restrict__ pos, const int* __restrict__ flagp, float4* __restrict__ posf)
{
  int bf = flagp[0];
  int i = blockIdx.x*256 + threadIdx.x;
  if (i < NN){
    float4 v;
    v.x = ldf(pos, 3*i+0, bf); v.y = ldf(pos, 3*i+1, bf); v.z = ldf(pos, 3*i+2, bf); v.w = 0.f;
    posf[i] = v;
  }
}

// ---------------- CSR build ----------------
extern "C" __global__ __launch_bounds__(256)
void k_deg(const int* __restrict__ eidx, int* __restrict__ deg)
{
  int e = blockIdx.x*256 + threadIdx.x;
  if (e < NE) atomicAdd(&deg[eidx[NE + e]], 1);
}

extern "C" __global__ __launch_bounds__(256)
void k_scan_a(const int* __restrict__ deg, int* __restrict__ bsum)
{
  __shared__ int s[256];
  int tid = threadIdx.x;
  int i = blockIdx.x*256 + tid;
  s[tid] = (i < NN) ? deg[i] : 0;
  __syncthreads();
  for (int d = 128; d > 0; d >>= 1){
    if (tid < d) s[tid] += s[tid + d];
    __syncthreads();
  }
  if (tid == 0) bsum[blockIdx.x] = s[0];
}

extern "C" __global__ __launch_bounds__(128)
void k_scan_b(const int* __restrict__ bsum, int* __restrict__ boff)
{
  __shared__ int s[128];
  int tid = threadIdx.x;
  int v = (tid < 79) ? bsum[tid] : 0;
  s[tid] = v;
  __syncthreads();
  for (int d = 1; d < 128; d <<= 1){
    int t = (tid >= d) ? s[tid - d] : 0;
    __syncthreads();
    s[tid] += t;
    __syncthreads();
  }
  if (tid < 79) boff[tid] = s[tid] - v;
}

extern "C" __global__ __launch_bounds__(256)
void k_scan_c(const int* __restrict__ deg, const int* __restrict__ boff, int* __restrict__ offs)
{
  __shared__ int s[256];
  int tid = threadIdx.x;
  int i = blockIdx.x*256 + tid;
  int v = (i < NN) ? deg[i] : 0;
  s[tid] = v;
  __syncthreads();
  for (int d = 1; d < 256; d <<= 1){
    int t = (tid >= d) ? s[tid - d] : 0;
    __syncthreads();
    s[tid] += t;
    __syncthreads();
  }
  if (i < NN) offs[i] = boff[blockIdx.x] + s[tid] - v;
}

extern "C" __global__ __launch_bounds__(256)
void k_scatter(const int* __restrict__ eidx, const int* __restrict__ offs,
               int* __restrict__ cur, int* __restrict__ elist)
{
  int e = blockIdx.x*256 + threadIdx.x;
  if (e < NE){
    int r = eidx[NE + e];
    int p = atomicAdd(&cur[r], 1);
    elist[offs[r] + p] = e;
  }
}

// ---------------- edge geometry ----------------
__device__ __forceinline__ void edge_geom(float4 pr, float4 ps, float* ef, float* Y)
{
  float vx = pr.x - ps.x, vy = pr.y - ps.y, vz = pr.z - ps.z;
  float r2 = vx*vx + vy*vy + vz*vz + 1e-12f;
  float rinv = rsqrtf(r2);
  float r = r2 * rinv;
  float ux = vx*rinv, uy = vy*rinv, uz = vz*rinv;
  const float s3 = 1.7320508076f, s5 = 2.2360679775f, s15 = 3.8729833462f;
  Y[0] = 1.0f;
  Y[1] = s3*ux; Y[2] = s3*uy; Y[3] = s3*uz;
  Y[4] = s15*ux*uy; Y[5] = s15*uy*uz;
  Y[6] = 0.5f*s5*(3.0f*uz*uz - 1.0f);
  Y[7] = s15*ux*uz;
  Y[8] = 0.5f*s15*(ux*ux - uy*uy);
  float u = r * 0.2f; u = fminf(u, 1.0f);
  float u2 = u*u, u4 = u2*u2, u6 = u4*u2, u7 = u6*u, u8 = u7*u;
  float fc = 1.0f - 28.0f*u6 + 48.0f*u7 - 21.0f*u8;
  float c0 = 0.63245553203f * fc * rinv;     // sqrt(2/RMAX)*fcut/r
  float w = 0.62831853072f * r;              // pi*r/RMAX
  #pragma unroll
  for (int k = 0; k < 8; ++k) ef[k] = c0 * __sinf(w * (float)(k + 1));
}

// ---------------- main fused kernel ----------------
// R7 structure (5000 blocks x 256 threads, 1 node/wave, batched gather,
// 3-slot pipeline = 3 syncs/edge) with ONE fix: ebuf halved to 32 entries so
// LDS = 52,144 B <= 26 x 2KB granules -> 3 blocks/CU (R7's 54,272 rounded to
// 27 granules -> only 2 blocks/CU; that cliff ate the per-wave win).
// R8's 512-thread variant spilled (VGPR 64, WRITE 6.6 GB) — abandoned.
extern "C" __global__ __launch_bounds__(256, 3)
void k_main(const int* __restrict__ atom, const int* __restrict__ eidx,
            const void* __restrict__ w1g, const void* __restrict__ w2g,
            const void* __restrict__ w3g, const void* __restrict__ w4g,
            const void* __restrict__ Wc3, const void* __restrict__ Wc2, const void* __restrict__ Wc1,
            const void* __restrict__ Woutg,
            const float* __restrict__ Hws, const float* __restrict__ U3ws,
            const float* __restrict__ U2ws, const float* __restrict__ U1ws,
            const float4* __restrict__ posf,
            const int* __restrict__ deg, const int* __restrict__ offs, const int* __restrict__ elist,
            const int* __restrict__ flagp, void* __restrict__ outp)
{
  __shared__ __align__(16) u16  w2s[8][64][8];     // [k8][j][k%8]       8192 B
  __shared__ __align__(16) u16  w3s[8][64][8];     //                    8192 B
  __shared__ __align__(16) u16  w4s[8][3][64][8];  // [k8][l][c][k%8]   24576 B; f32 W_out at epilogue
  __shared__ __align__(16) float Hs[10][64];       //                    2560 B
  __shared__ __align__(16) float U3t[165][4];      //                    2640 B
  __shared__ __align__(16) float U2t[45][4];       //                     720 B
  __shared__ __align__(16) float U1t[9][4];        //                     144 B
  __shared__ __align__(16) float fbuf[4][3][64];   // 3-slot pipeline    3072 B
  __shared__ __align__(16) float4 ebuf[4][32];     // edge cache (32!)   2048 B  -> total ~52.1 KB

  int bf = flagp[0];
  int tid = threadIdx.x;
  for (int t = tid; t < 4096; t += 256){
    int k = t >> 6, j = t & 63;
    u16 v2 = bf ? ((const u16*)w2g)[t] : f2bf(((const float*)w2g)[t]);
    u16 v3 = bf ? ((const u16*)w3g)[t] : f2bf(((const float*)w3g)[t]);
    w2s[k>>3][j][k&7] = v2;
    w3s[k>>3][j][k&7] = v3;
  }
  for (int t = tid; t < 12288; t += 256){
    int k = t / 192, col = t % 192;
    u16 v4 = bf ? ((const u16*)w4g)[t] : f2bf(((const float*)w4g)[t]);
    w4s[k>>3][col>>6][col&63][k&7] = v4;
  }
  for (int t = tid; t < 640; t += 256) ((float*)Hs)[t]  = Hws[t];
  for (int t = tid; t < 660; t += 256) ((float*)U3t)[t] = U3ws[t];
  for (int t = tid; t < 180; t += 256) ((float*)U2t)[t] = U2ws[t];
  for (int t = tid; t < 36;  t += 256) ((float*)U1t)[t] = U1ws[t];
  __syncthreads();

  int wv = tid >> 6;
  int lane = tid & 63;
  int n = blockIdx.x * 4 + wv;
  int start = offs[n];
  int cnt = deg[n];
  float4 pr = posf[n];

  // L1 weights live in registers (saves 8 LDS reads per edge)
  float w1r[8];
  #pragma unroll
  for (int k = 0; k < 8; ++k) w1r[k] = ldf(w1g, k*64 + lane, bf);

  const float4* fbS0 = (const float4*)&fbuf[wv][0][0];
  const float4* fbS1 = (const float4*)&fbuf[wv][1][0];
  const float4* fbS2 = (const float4*)&fbuf[wv][2][0];

  float X[9];
  #pragma unroll
  for (int m = 0; m < 9; ++m) X[m] = 0.f;

  // Outer: 32-edge batches (avg degree 16 -> usually one batch per node).
  #pragma unroll 1
  for (int base = 0; base < cnt; base += 32){
    int nb = min(cnt - base, 32);

    // ---- batched parallel gather: lane j (j<32) resolves edge base+j's chain ----
    if (lane < nb){
      int e = elist[start + base + lane];   // coalesced
      int s = eidx[e];                      // parallel gather
      float4 p = posf[s];                   // parallel gather
      p.w = __int_as_float(atom[s]);        // parallel gather
      ebuf[wv][lane] = p;
    }
    WAVE_SYNC();

    // ---- per-edge MLP loop; edge data via broadcast LDS reads ----
    for (int i = 0; i < nb; ++i){
      float4 q = ebuf[wv][i];
      int z = __float_as_int(q.w);

      float ef[8], Y[9];
      edge_geom(pr, q, ef, Y);

      // ---- L1: 8 -> 64 (weights in regs) -> S0 ----
      float a = 0.f;
      #pragma unroll
      for (int k = 0; k < 8; ++k) a += ef[k] * w1r[k];
      a = silu_f(a);
      fbuf[wv][0][lane] = a;
      WAVE_SYNC();

      // ---- L2: 64 -> 64, S0 -> S1 ----
      {
        float p0 = 0.f, p1 = 0.f;
        #pragma unroll
        for (int k8 = 0; k8 < 8; ++k8){
          uint4 w = *(const uint4*)&w2s[k8][lane][0];
          float4 f0 = fbS0[2*k8], f1 = fbS0[2*k8+1];
          p0 += bflo(w.x)*f0.x + bfhi(w.x)*f0.y + bflo(w.y)*f0.z + bfhi(w.y)*f0.w;
          p1 += bflo(w.z)*f1.x + bfhi(w.z)*f1.y + bflo(w.w)*f1.z + bfhi(w.w)*f1.w;
        }
        a = silu_f(p0 + p1);
      }
      fbuf[wv][1][lane] = a;
      WAVE_SYNC();

      // ---- L3: 64 -> 64, S1 -> S2 ----
      {
        float p0 = 0.f, p1 = 0.f;
        #pragma unroll
        for (int k8 = 0; k8 < 8; ++k8){
          uint4 w = *(const uint4*)&w3s[k8][lane][0];
          float4 f0 = fbS1[2*k8], f1 = fbS1[2*k8+1];
          p0 += bflo(w.x)*f0.x + bfhi(w.x)*f0.y + bflo(w.y)*f0.z + bfhi(w.y)*f0.w;
          p1 += bflo(w.z)*f1.x + bfhi(w.z)*f1.y + bflo(w.w)*f1.z + bfhi(w.w)*f1.w;
        }
        a = silu_f(p0 + p1);
      }
      fbuf[wv][2][lane] = a;
      WAVE_SYNC();

      // ---- L4: 64 -> 192 (tpw[l][lane]), reads S2; no trailing sync needed:
      // next L1 writes S0 (readers drained 2 syncs ago); next-edge syncs
      // drain these S2 reads before S2 is rewritten. ----
      float t0 = 0.f, t1 = 0.f, t2 = 0.f;
      #pragma unroll
      for (int k8 = 0; k8 < 8; ++k8){
        float4 f0 = fbS2[2*k8], f1 = fbS2[2*k8+1];
        uint4 qa = *(const uint4*)&w4s[k8][0][lane][0];
        t0 += bflo(qa.x)*f0.x + bfhi(qa.x)*f0.y + bflo(qa.y)*f0.z + bfhi(qa.y)*f0.w
            + bflo(qa.z)*f1.x + bfhi(qa.z)*f1.y + bflo(qa.w)*f1.z + bfhi(qa.w)*f1.w;
        uint4 qb = *(const uint4*)&w4s[k8][1][lane][0];
        t1 += bflo(qb.x)*f0.x + bfhi(qb.x)*f0.y + bflo(qb.y)*f0.z + bfhi(qb.y)*f0.w
            + bflo(qb.z)*f1.x + bfhi(qb.z)*f1.y + bflo(qb.w)*f1.z + bfhi(qb.w)*f1.w;
        uint4 qc = *(const uint4*)&w4s[k8][2][lane][0];
        t2 += bflo(qc.x)*f0.x + bfhi(qc.x)*f0.y + bflo(qc.y)*f0.z + bfhi(qc.y)*f0.w
            + bflo(qc.z)*f1.x + bfhi(qc.z)*f1.y + bflo(qc.w)*f1.z + bfhi(qc.w)*f1.w;
      }

      // ---- accumulate messages ----
      float h = Hs[z][lane];
      float q0 = h*t0, q1 = h*t1, q2 = h*t2;
      X[0] += q0*Y[0];
      X[1] += q1*Y[1]; X[2] += q1*Y[2]; X[3] += q1*Y[3];
      X[4] += q2*Y[4]; X[5] += q2*Y[5]; X[6] += q2*Y[6];
      X[7] += q2*Y[7]; X[8] += q2*Y[8];
    }
  }

  #pragma unroll
  for (int m = 0; m < 9; ++m) X[m] *= 0.0625f;   // / AVG

  // ---- contraction (rolled to keep VGPRs low) ----
  float s1a[4] = {0,0,0,0}, s2a[4] = {0,0,0,0}, s3a[4] = {0,0,0,0};
  #pragma unroll
  for (int j = 0; j < 9; ++j){
    float4 u = *(const float4*)&U1t[j][0];
    s1a[0] += u.x*X[j]; s1a[1] += u.y*X[j]; s1a[2] += u.z*X[j]; s1a[3] += u.w*X[j];
  }
  {
    int t2i = 0;
    #pragma unroll 1
    for (int j = 0; j < 9; ++j){
      #pragma unroll 1
      for (int k = j; k < 9; ++k){
        float m = X[j]*X[k];
        float4 u = *(const float4*)&U2t[t2i][0]; ++t2i;
        s2a[0] += u.x*m; s2a[1] += u.y*m; s2a[2] += u.z*m; s2a[3] += u.w*m;
      }
    }
  }
  {
    int t3i = 0;
    #pragma unroll 1
    for (int i = 0; i < 9; ++i){
      #pragma unroll 1
      for (int j = i; j < 9; ++j){
        float mij = X[i]*X[j];
        #pragma unroll 1
        for (int k = j; k < 9; ++k){
          float m = mij*X[k];
          float4 u = *(const float4*)&U3t[t3i][0]; ++t3i;
          s3a[0] += u.x*m; s3a[1] += u.y*m; s3a[2] += u.z*m; s3a[3] += u.w*m;
        }
      }
    }
  }

  int zn = atom[n];
  float outval = 0.f;
  #pragma unroll
  for (int p = 0; p < 4; ++p){
    int base = (zn*4 + p)*64 + lane;
    outval += ldf(Wc1, base, bf)*s1a[p] + ldf(Wc2, base, bf)*s2a[p] + ldf(Wc3, base, bf)*s3a[p];
  }

  // ---- fused final matmul: restage W_out (f32) into the w4s LDS region ----
  __syncthreads();                    // all waves done reading w4s
  float* wos = (float*)&w4s[0][0][0][0];   // 16 KB <= 24 KB region
  for (int t = tid; t < 4096; t += 256) wos[t] = ldf(Woutg, t, bf);
  __syncthreads();

  fbuf[wv][0][lane] = outval;
  WAVE_SYNC();
  float acc = 0.f;
  #pragma unroll
  for (int cb = 0; cb < 16; ++cb){
    float4 p = fbS0[cb];
    acc += p.x*wos[(4*cb+0)*64 + lane] + p.y*wos[(4*cb+1)*64 + lane]
         + p.z*wos[(4*cb+2)*64 + lane] + p.w*wos[(4*cb+3)*64 + lane];
  }
  acc *= 0.125f;
  if (bf) ((u16*)outp)[n*64 + lane] = f2bf(acc);
  else    ((float*)outp)[n*64 + lane] = acc;
}

// ---------------- host ----------------
extern "C" void kernel_launch(void* const* d_in, const int* in_sizes, int n_in,
                              void* d_out, int out_size, void* d_ws, size_t ws_size,
                              hipStream_t stream)
{
  const void* pos  = d_in[0];
  const int* atom  = (const int*)d_in[1];
  const int* eidx  = (const int*)d_in[2];
  const void* We   = d_in[3];
  const void* Wu   = d_in[4];
  const void* w1g  = d_in[5];
  const void* w2g  = d_in[6];
  const void* w3g  = d_in[7];
  const void* w4g  = d_in[8];
  const void* U3   = d_in[9];
  const void* U2   = d_in[10];
  const void* U1   = d_in[11];
  const void* Wc3  = d_in[12];
  const void* Wc2  = d_in[13];
  const void* Wc1  = d_in[14];
  const void* Wout = d_in[15];

  char* ws = (char*)d_ws;
  int*    flag  = (int*)(ws + WS_FLAG);
  float*  Hws   = (float*)(ws + WS_H);
  float*  U1ws  = (float*)(ws + WS_U1);
  float*  U2ws  = (float*)(ws + WS_U2);
  float*  U3ws  = (float*)(ws + WS_U3);
  int*    deg   = (int*)(ws + WS_DEG);
  int*    cur   = (int*)(ws + WS_CUR);
  int*    offs  = (int*)(ws + WS_OFF);
  int*    bsum  = (int*)(ws + WS_BSUM);
  int*    boff  = (int*)(ws + WS_BOFF);
  int*    elist = (int*)(ws + WS_ELIST);
  float4* posf  = (float4*)(ws + WS_POSF);

  (void)hipMemsetAsync(ws + WS_DEG, 0, 160000, stream);   // deg + cur

  k_sniff<<<1, 256, 0, stream>>>((const u32*)Wu, flag);
  k_prep<<<1, 256, 0, stream>>>(We, Wu, U3, U2, U1, flag, Hws, U3ws, U2ws, U1ws);
  k_pos<<<79, 256, 0, stream>>>(pos, flag, posf);
  k_deg<<<1250, 256, 0, stream>>>(eidx, deg);
  k_scan_a<<<79, 256, 0, stream>>>(deg, bsum);
  k_scan_b<<<1, 128, 0, stream>>>(bsum, boff);
  k_scan_c<<<79, 256, 0, stream>>>(deg, boff, offs);
  k_scatter<<<1250, 256, 0, stream>>>(eidx, offs, cur, elist);
  k_main<<<5000, 256, 0, stream>>>(atom, eidx, w1g, w2g, w3g, w4g, Wc3, Wc2, Wc1, Wout,
                                   Hws, U3ws, U2ws, U1ws, posf, deg, offs, elist,
                                   flag, d_out);
}

// Round 10
// 484.001 us; speedup vs baseline: 5.0240x; 2.8811x over previous
//
#include <hip/hip_runtime.h>

typedef unsigned short u16;
typedef unsigned int u32;
typedef __attribute__((ext_vector_type(8))) short bf16x8;
typedef __attribute__((ext_vector_type(4))) float f32x4;

#define NN 20000
#define NE 320000

// ---------------- workspace layout (bytes) ----------------
#define WS_FLAG  0         // 1 i32: 1 = inputs are bf16, 0 = f32 (R4 proved f32)
#define WS_H     256       // 640 f32   H[z][c]
#define WS_U1    3072      // 36  f32
#define WS_U2    3328      // 180 f32   U2sym[45][4]
#define WS_U3    4096      // 660 f32   U3sym[165][4]
#define WS_DEG   7168      // 20000 i32
#define WS_CUR   87168     // 20000 i32
#define WS_OFF   167168    // 20000 i32
#define WS_BSUM  247168    // 79 i32
#define WS_BOFF  247552    // 79 i32
#define WS_ELIST 248064    // 320000 i32
#define WS_POSF  1528064   // 20000 float4
#define WS_WB    1848064   // 22528 u16: 44 MFMA B-frags (w1:4, w2:8, w3:8, w4:24)

__device__ __forceinline__ float bf2f(u16 u){ return __uint_as_float(((u32)u) << 16); }
__device__ __forceinline__ u16 f2bf(float f){
  u32 u = __float_as_uint(f);
  u32 r = (u + 0x7fffu + ((u >> 16) & 1u)) >> 16;
  return (u16)r;
}
__device__ __forceinline__ float silu_f(float v){ return v / (1.0f + __expf(-v)); }
__device__ __forceinline__ float ldf(const void* p, int i, int bf){
  return bf ? bf2f(((const u16*)p)[i]) : ((const float*)p)[i];
}
__device__ __forceinline__ f32x4 mfma16(bf16x8 a, bf16x8 b, f32x4 c){
  return __builtin_amdgcn_mfma_f32_16x16x32_bf16(a, b, c, 0, 0, 0);
}

// Wave-synchronous LDS fence (proven R4-R9).
#define WAVE_SYNC() do { \
  __builtin_amdgcn_wave_barrier(); \
  asm volatile("s_waitcnt lgkmcnt(0)" ::: "memory"); \
  __builtin_amdgcn_wave_barrier(); \
} while (0)

// ---------------- dtype sniffer ----------------
extern "C" __global__ __launch_bounds__(256)
void k_sniff(const u32* __restrict__ wu, int* __restrict__ flag)
{
  __shared__ int s[256];
  int tid = threadIdx.x;
  u32 w = wu[tid];
  u32 e = (w >> 7) & 0xFFu;
  s[tid] = (e >= 0x60u && e <= 0x86u) ? 1 : 0;
  __syncthreads();
  for (int d = 128; d > 0; d >>= 1){
    if (tid < d) s[tid] += s[tid + d];
    __syncthreads();
  }
  if (tid == 0) flag[0] = (s[0] > 148) ? 1 : 0;
}

// ---------------- prep: H, U tables + MFMA B-frag weight packing ----------------
// B-frag layout (16x16x32): lane L holds B[k=(L>>4)*8+j][n=L&15], j=0..7.
// frag order: w1 t=0..3 (K=32, k<8 nonzero) | w2 f=4+t*2+q | w3 f=12+t*2+q |
//             w4 f=20+(l*4+ct)*2+q  (col = l*64 + ct*16 + n)
extern "C" __global__ __launch_bounds__(256)
void k_prep(const void* __restrict__ We, const void* __restrict__ Wu,
            const void* __restrict__ U3, const void* __restrict__ U2, const void* __restrict__ U1,
            const void* __restrict__ w1, const void* __restrict__ w2,
            const void* __restrict__ w3, const void* __restrict__ w4,
            const int* __restrict__ flagp,
            float* __restrict__ Hws, float* __restrict__ U3ws,
            float* __restrict__ U2ws, float* __restrict__ U1ws,
            u16* __restrict__ wbws)
{
  int bf = flagp[0];
  int tid = threadIdx.x;
  for (int t = tid; t < 640; t += 256){
    int z = t >> 6, c = t & 63;
    float s = 0.f;
    for (int k = 0; k < 64; ++k) s += ldf(We, z*64 + k, bf) * ldf(Wu, k*64 + c, bf);
    Hws[t] = s * 0.0395284708f;   // 1/sqrt(Z*C)
  }
  for (int t = tid; t < 36; t += 256) U1ws[t] = ldf(U1, t, bf);
  for (int t = tid; t < 45; t += 256){
    int j = 0, rem = t;
    for (;;){ int cnt = 9 - j; if (rem < cnt) break; rem -= cnt; ++j; }
    int k = j + rem;
    for (int p = 0; p < 4; ++p){
      float v = ldf(U2, (j*9 + k)*4 + p, bf);
      if (k > j) v += ldf(U2, (k*9 + j)*4 + p, bf);
      U2ws[t*4 + p] = v;
    }
  }
  for (int t = tid; t < 165; t += 256){
    int i = 0, rem = t;
    for (;;){ int m = 9 - i; int cnt = m*(m+1)/2; if (rem < cnt) break; rem -= cnt; ++i; }
    int j = i;
    for (;;){ int cnt = 9 - j; if (rem < cnt) break; rem -= cnt; ++j; }
    int k = j + rem;
    int pm[6][3] = {{i,j,k},{i,k,j},{j,i,k},{j,k,i},{k,i,j},{k,j,i}};
    float acc[4] = {0,0,0,0};
    for (int m = 0; m < 6; ++m){
      bool dup = false;
      for (int mm = 0; mm < m; ++mm)
        if (pm[mm][0]==pm[m][0] && pm[mm][1]==pm[m][1] && pm[mm][2]==pm[m][2]) dup = true;
      if (!dup){
        int base = ((pm[m][0]*9 + pm[m][1])*9 + pm[m][2])*4;
        for (int p = 0; p < 4; ++p) acc[p] += ldf(U3, base + p, bf);
      }
    }
    for (int p = 0; p < 4; ++p) U3ws[t*4 + p] = acc[p];
  }
  // ---- B-frag packing: 44 frags x 64 lanes x 8 elems ----
  for (int idx = tid; idx < 22528; idx += 256){
    int f = idx >> 9;
    int L = (idx >> 3) & 63;
    int j = idx & 7;
    int kl = ((L >> 4) << 3) + j;   // k within a 32-chunk
    int n16 = L & 15;
    float v;
    if (f < 4){
      v = (kl < 8) ? ldf(w1, kl*64 + (f*16 + n16), bf) : 0.f;
    } else if (f < 12){
      int g = f - 4; int t = g >> 1, q = g & 1;
      v = ldf(w2, (q*32 + kl)*64 + (t*16 + n16), bf);
    } else if (f < 20){
      int g = f - 12; int t = g >> 1, q = g & 1;
      v = ldf(w3, (q*32 + kl)*64 + (t*16 + n16), bf);
    } else {
      int g = f - 20; int lt = g >> 1, q = g & 1;
      int l = lt >> 2, ct = lt & 3;
      v = ldf(w4, (q*32 + kl)*192 + (l*64 + ct*16 + n16), bf);
    }
    wbws[idx] = f2bf(v);
  }
}

// ---------------- positions -> float4 ----------------
extern "C" __global__ __launch_bounds__(256)
void k_pos(const void* __restrict__ pos, const int* __restrict__ flagp, float4* __restrict__ posf)
{
  int bf = flagp[0];
  int i = blockIdx.x*256 + threadIdx.x;
  if (i < NN){
    float4 v;
    v.x = ldf(pos, 3*i+0, bf); v.y = ldf(pos, 3*i+1, bf); v.z = ldf(pos, 3*i+2, bf); v.w = 0.f;
    posf[i] = v;
  }
}

// ---------------- CSR build ----------------
extern "C" __global__ __launch_bounds__(256)
void k_deg(const int* __restrict__ eidx, int* __restrict__ deg)
{
  int e = blockIdx.x*256 + threadIdx.x;
  if (e < NE) atomicAdd(&deg[eidx[NE + e]], 1);
}

extern "C" __global__ __launch_bounds__(256)
void k_scan_a(const int* __restrict__ deg, int* __restrict__ bsum)
{
  __shared__ int s[256];
  int tid = threadIdx.x;
  int i = blockIdx.x*256 + tid;
  s[tid] = (i < NN) ? deg[i] : 0;
  __syncthreads();
  for (int d = 128; d > 0; d >>= 1){
    if (tid < d) s[tid] += s[tid + d];
    __syncthreads();
  }
  if (tid == 0) bsum[blockIdx.x] = s[0];
}

extern "C" __global__ __launch_bounds__(128)
void k_scan_b(const int* __restrict__ bsum, int* __restrict__ boff)
{
  __shared__ int s[128];
  int tid = threadIdx.x;
  int v = (tid < 79) ? bsum[tid] : 0;
  s[tid] = v;
  __syncthreads();
  for (int d = 1; d < 128; d <<= 1){
    int t = (tid >= d) ? s[tid - d] : 0;
    __syncthreads();
    s[tid] += t;
    __syncthreads();
  }
  if (tid < 79) boff[tid] = s[tid] - v;
}

extern "C" __global__ __launch_bounds__(256)
void k_scan_c(const int* __restrict__ deg, const int* __restrict__ boff, int* __restrict__ offs)
{
  __shared__ int s[256];
  int tid = threadIdx.x;
  int i = blockIdx.x*256 + tid;
  int v = (i < NN) ? deg[i] : 0;
  s[tid] = v;
  __syncthreads();
  for (int d = 1; d < 256; d <<= 1){
    int t = (tid >= d) ? s[tid - d] : 0;
    __syncthreads();
    s[tid] += t;
    __syncthreads();
  }
  if (i < NN) offs[i] = boff[blockIdx.x] + s[tid] - v;
}

extern "C" __global__ __launch_bounds__(256)
void k_scatter(const int* __restrict__ eidx, const int* __restrict__ offs,
               int* __restrict__ cur, int* __restrict__ elist)
{
  int e = blockIdx.x*256 + threadIdx.x;
  if (e < NE){
    int r = eidx[NE + e];
    int p = atomicAdd(&cur[r], 1);
    elist[offs[r] + p] = e;
  }
}

// ---------------- edge geometry ----------------
__device__ __forceinline__ void edge_geom(float4 pr, float4 ps, float* ef, float* Y)
{
  float vx = pr.x - ps.x, vy = pr.y - ps.y, vz = pr.z - ps.z;
  float r2 = vx*vx + vy*vy + vz*vz + 1e-12f;
  float rinv = rsqrtf(r2);
  float r = r2 * rinv;
  float ux = vx*rinv, uy = vy*rinv, uz = vz*rinv;
  const float s3 = 1.7320508076f, s5 = 2.2360679775f, s15 = 3.8729833462f;
  Y[0] = 1.0f;
  Y[1] = s3*ux; Y[2] = s3*uy; Y[3] = s3*uz;
  Y[4] = s15*ux*uy; Y[5] = s15*uy*uz;
  Y[6] = 0.5f*s5*(3.0f*uz*uz - 1.0f);
  Y[7] = s15*ux*uz;
  Y[8] = 0.5f*s15*(ux*ux - uy*uy);
  float u = r * 0.2f; u = fminf(u, 1.0f);
  float u2 = u*u, u4 = u2*u2, u6 = u4*u2, u7 = u6*u, u8 = u7*u;
  float fc = 1.0f - 28.0f*u6 + 48.0f*u7 - 21.0f*u8;
  float c0 = 0.63245553203f * fc * rinv;
  float w = 0.62831853072f * r;
  #pragma unroll
  for (int k = 0; k < 8; ++k) ef[k] = c0 * __sinf(w * (float)(k + 1));
}

// ---------------- main fused kernel: MFMA edge-tile MLP ----------------
// One node per wave, 16-edge MFMA tiles. Per tile: geometry (lanes 0-15) ->
// L1..L3 via mfma_f32_16x16x32_bf16 with act[16][64] bf16 LDS transpose ->
// L4 per l-chunk with X-partials accumulated straight from D fragments ->
// once per node: shfl_xor quad-reduce + select. LDS 63.4 KB -> 2 blocks/CU.
extern "C" __global__ __launch_bounds__(256, 2)
void k_main(const int* __restrict__ atom, const int* __restrict__ eidx,
            const void* __restrict__ Wc3, const void* __restrict__ Wc2, const void* __restrict__ Wc1,
            const void* __restrict__ Woutg,
            const float* __restrict__ Hws, const float* __restrict__ U3ws,
            const float* __restrict__ U2ws, const float* __restrict__ U1ws,
            const float4* __restrict__ posf,
            const int* __restrict__ deg, const int* __restrict__ offs, const int* __restrict__ elist,
            const u16* __restrict__ wbws, const int* __restrict__ flagp, void* __restrict__ outp)
{
  __shared__ __align__(16) u16   wb[22528];      // 44 B-frags (45056 B); f32 W_out at epilogue
  __shared__ __align__(16) u16   efb[4][16][8];  // per-wave edge features bf16
  __shared__ __align__(16) float Yb[4][16][12];  // per-wave Y[9] + z bits at [9]
  __shared__ __align__(16) u16   act[4][16][64]; // per-wave activations bf16 [edge][k]
  __shared__ __align__(16) float Hs[10][64];
  __shared__ __align__(16) float U3t[165][4];
  __shared__ __align__(16) float U2t[45][4];
  __shared__ __align__(16) float U1t[9][4];

  int bf = flagp[0];
  int tid = threadIdx.x;
  for (int t = tid; t < 11264; t += 256) ((u32*)wb)[t] = ((const u32*)wbws)[t];
  for (int t = tid; t < 640; t += 256) ((float*)Hs)[t]  = Hws[t];
  for (int t = tid; t < 660; t += 256) ((float*)U3t)[t] = U3ws[t];
  for (int t = tid; t < 180; t += 256) ((float*)U2t)[t] = U2ws[t];
  for (int t = tid; t < 36;  t += 256) ((float*)U1t)[t] = U1ws[t];
  __syncthreads();

  int wv = tid >> 6;
  int lane = tid & 63;
  int c0 = lane & 15;
  int qd = lane >> 4;
  int n = blockIdx.x * 4 + wv;
  int start = offs[n];
  int cnt = deg[n];
  float4 pr = posf[n];

  // Preload w1/w2/w3 B-frags into registers (static across all tiles).
  bf16x8 w1r[4], w2r[8], w3r[8];
  #pragma unroll
  for (int t = 0; t < 4; ++t) w1r[t] = *(const bf16x8*)&wb[t*512 + lane*8];
  #pragma unroll
  for (int g = 0; g < 8; ++g) w2r[g] = *(const bf16x8*)&wb[(4+g)*512 + lane*8];
  #pragma unroll
  for (int g = 0; g < 8; ++g) w3r[g] = *(const bf16x8*)&wb[(12+g)*512 + lane*8];

  float Xp[4][9];
  #pragma unroll
  for (int t = 0; t < 4; ++t)
    #pragma unroll
    for (int m = 0; m < 9; ++m) Xp[t][m] = 0.f;

  const f32x4 zero4 = {0.f, 0.f, 0.f, 0.f};

  #pragma unroll 1
  for (int base = 0; base < cnt; base += 16){
    int nb = min(cnt - base, 16);
    WAVE_SYNC();                       // drain prior tile's efb/Yb readers
    if (lane < 16){
      bool valid = lane < nb;
      int e = elist[start + base + (valid ? lane : 0)];
      int s = eidx[e];
      float4 ps = posf[s];
      int z = valid ? atom[s] : 0;
      float ef[8], Y[9];
      edge_geom(pr, ps, ef, Y);
      if (!valid){
        #pragma unroll
        for (int k = 0; k < 8; ++k) ef[k] = 0.f;
      }
      uint4 pk;
      pk.x = (u32)f2bf(ef[0]) | ((u32)f2bf(ef[1]) << 16);
      pk.y = (u32)f2bf(ef[2]) | ((u32)f2bf(ef[3]) << 16);
      pk.z = (u32)f2bf(ef[4]) | ((u32)f2bf(ef[5]) << 16);
      pk.w = (u32)f2bf(ef[6]) | ((u32)f2bf(ef[7]) << 16);
      *(uint4*)&efb[wv][lane][0] = pk;
      #pragma unroll
      for (int m = 0; m < 9; ++m) Yb[wv][lane][m] = Y[m];
      Yb[wv][lane][9] = __int_as_float(z);
    }
    WAVE_SYNC();

    f32x4 dd[4];

    // ---- L1: A[e][k<32] (k<8 = ef, else 0) x W1 ----
    bf16x8 aF = {0,0,0,0,0,0,0,0};
    if (lane < 16) aF = *(const bf16x8*)&efb[wv][lane][0];
    #pragma unroll
    for (int t = 0; t < 4; ++t) dd[t] = mfma16(aF, w1r[t], zero4);
    #pragma unroll
    for (int t = 0; t < 4; ++t)
      #pragma unroll
      for (int r = 0; r < 4; ++r)
        act[wv][qd*4 + r][c0 + 16*t] = f2bf(silu_f(dd[t][r]));
    WAVE_SYNC();

    // ---- L2 ----
    bf16x8 a0 = *(const bf16x8*)&act[wv][c0][qd*8];
    bf16x8 a1 = *(const bf16x8*)&act[wv][c0][32 + qd*8];
    #pragma unroll
    for (int t = 0; t < 4; ++t)
      dd[t] = mfma16(a1, w2r[t*2+1], mfma16(a0, w2r[t*2+0], zero4));
    #pragma unroll
    for (int t = 0; t < 4; ++t)
      #pragma unroll
      for (int r = 0; r < 4; ++r)
        act[wv][qd*4 + r][c0 + 16*t] = f2bf(silu_f(dd[t][r]));
    WAVE_SYNC();

    // ---- L3 ----
    a0 = *(const bf16x8*)&act[wv][c0][qd*8];
    a1 = *(const bf16x8*)&act[wv][c0][32 + qd*8];
    #pragma unroll
    for (int t = 0; t < 4; ++t)
      dd[t] = mfma16(a1, w3r[t*2+1], mfma16(a0, w3r[t*2+0], zero4));
    #pragma unroll
    for (int t = 0; t < 4; ++t)
      #pragma unroll
      for (int r = 0; r < 4; ++r)
        act[wv][qd*4 + r][c0 + 16*t] = f2bf(silu_f(dd[t][r]));
    WAVE_SYNC();

    // ---- L4 per l-chunk + direct X-partial accumulation ----
    a0 = *(const bf16x8*)&act[wv][c0][qd*8];
    a1 = *(const bf16x8*)&act[wv][c0][32 + qd*8];
    #pragma unroll
    for (int l = 0; l < 3; ++l){
      #pragma unroll
      for (int ct = 0; ct < 4; ++ct){
        int f = 20 + (l*4 + ct)*2;
        bf16x8 b0 = *(const bf16x8*)&wb[f*512 + lane*8];
        bf16x8 b1 = *(const bf16x8*)&wb[(f+1)*512 + lane*8];
        dd[ct] = mfma16(a1, b1, mfma16(a0, b0, zero4));
      }
      #pragma unroll
      for (int r = 0; r < 4; ++r){
        int e = qd*4 + r;
        int z_e = __float_as_int(Yb[wv][e][9]);
        float h0 = Hs[z_e][c0+ 0], h1 = Hs[z_e][c0+16];
        float h2 = Hs[z_e][c0+32], h3 = Hs[z_e][c0+48];
        float q0 = h0*dd[0][r], q1 = h1*dd[1][r];
        float q2 = h2*dd[2][r], q3 = h3*dd[3][r];
        if (l == 0){
          float y = Yb[wv][e][0];
          Xp[0][0] += q0*y; Xp[1][0] += q1*y; Xp[2][0] += q2*y; Xp[3][0] += q3*y;
        } else if (l == 1){
          #pragma unroll
          for (int m = 1; m <= 3; ++m){
            float y = Yb[wv][e][m];
            Xp[0][m] += q0*y; Xp[1][m] += q1*y; Xp[2][m] += q2*y; Xp[3][m] += q3*y;
          }
        } else {
          #pragma unroll
          for (int m = 4; m <= 8; ++m){
            float y = Yb[wv][e][m];
            Xp[0][m] += q0*y; Xp[1][m] += q1*y; Xp[2][m] += q2*y; Xp[3][m] += q3*y;
          }
        }
      }
    }
  }

  // ---- quad-reduce X-partials: sum lanes {L&15, +16, +32, +48}, pick own tile ----
  #pragma unroll
  for (int t = 0; t < 4; ++t)
    #pragma unroll
    for (int m = 0; m < 9; ++m){
      float v = Xp[t][m];
      v += __shfl_xor(v, 16, 64);
      v += __shfl_xor(v, 32, 64);
      Xp[t][m] = v;
    }
  float X[9];
  #pragma unroll
  for (int m = 0; m < 9; ++m){
    float x = Xp[0][m];
    x = (qd == 1) ? Xp[1][m] : x;
    x = (qd == 2) ? Xp[2][m] : x;
    x = (qd == 3) ? Xp[3][m] : x;
    X[m] = x * 0.0625f;                 // / AVG
  }

  // ---- contraction (rolled) ----
  float s1a[4] = {0,0,0,0}, s2a[4] = {0,0,0,0}, s3a[4] = {0,0,0,0};
  #pragma unroll
  for (int j = 0; j < 9; ++j){
    float4 u = *(const float4*)&U1t[j][0];
    s1a[0] += u.x*X[j]; s1a[1] += u.y*X[j]; s1a[2] += u.z*X[j]; s1a[3] += u.w*X[j];
  }
  {
    int t2i = 0;
    #pragma unroll 1
    for (int j = 0; j < 9; ++j){
      #pragma unroll 1
      for (int k = j; k < 9; ++k){
        float m = X[j]*X[k];
        float4 u = *(const float4*)&U2t[t2i][0]; ++t2i;
        s2a[0] += u.x*m; s2a[1] += u.y*m; s2a[2] += u.z*m; s2a[3] += u.w*m;
      }
    }
  }
  {
    int t3i = 0;
    #pragma unroll 1
    for (int i = 0; i < 9; ++i){
      #pragma unroll 1
      for (int j = i; j < 9; ++j){
        float mij = X[i]*X[j];
        #pragma unroll 1
        for (int k = j; k < 9; ++k){
          float m = mij*X[k];
          float4 u = *(const float4*)&U3t[t3i][0]; ++t3i;
          s3a[0] += u.x*m; s3a[1] += u.y*m; s3a[2] += u.z*m; s3a[3] += u.w*m;
        }
      }
    }
  }

  int zn = atom[n];
  float outval = 0.f;
  #pragma unroll
  for (int p = 0; p < 4; ++p){
    int b = (zn*4 + p)*64 + lane;
    outval += ldf(Wc1, b, bf)*s1a[p] + ldf(Wc2, b, bf)*s2a[p] + ldf(Wc3, b, bf)*s3a[p];
  }

  // ---- fused final matmul: restage W_out f32 into wb region ----
  __syncthreads();
  float* wos = (float*)wb;              // 16 KB <= 45 KB
  for (int t = tid; t < 4096; t += 256) wos[t] = ldf(Woutg, t, bf);
  __syncthreads();

  float* xchg = (float*)&act[wv][0][0]; // 256 B <= 2 KB per-wave region
  xchg[lane] = outval;
  WAVE_SYNC();
  float acc = 0.f;
  const float4* pb = (const float4*)xchg;
  #pragma unroll
  for (int cb = 0; cb < 16; ++cb){
    float4 p = pb[cb];
    acc += p.x*wos[(4*cb+0)*64 + lane] + p.y*wos[(4*cb+1)*64 + lane]
         + p.z*wos[(4*cb+2)*64 + lane] + p.w*wos[(4*cb+3)*64 + lane];
  }
  acc *= 0.125f;
  if (bf) ((u16*)outp)[n*64 + lane] = f2bf(acc);
  else    ((float*)outp)[n*64 + lane] = acc;
}

// ---------------- host ----------------
extern "C" void kernel_launch(void* const* d_in, const int* in_sizes, int n_in,
                              void* d_out, int out_size, void* d_ws, size_t ws_size,
                              hipStream_t stream)
{
  const void* pos  = d_in[0];
  const int* atom  = (const int*)d_in[1];
  const int* eidx  = (const int*)d_in[2];
  const void* We   = d_in[3];
  const void* Wu   = d_in[4];
  const void* w1g  = d_in[5];
  const void* w2g  = d_in[6];
  const void* w3g  = d_in[7];
  const void* w4g  = d_in[8];
  const void* U3   = d_in[9];
  const void* U2   = d_in[10];
  const void* U1   = d_in[11];
  const void* Wc3  = d_in[12];
  const void* Wc2  = d_in[13];
  const void* Wc1  = d_in[14];
  const void* Wout = d_in[15];

  char* ws = (char*)d_ws;
  int*    flag  = (int*)(ws + WS_FLAG);
  float*  Hws   = (float*)(ws + WS_H);
  float*  U1ws  = (float*)(ws + WS_U1);
  float*  U2ws  = (float*)(ws + WS_U2);
  float*  U3ws  = (float*)(ws + WS_U3);
  int*    deg   = (int*)(ws + WS_DEG);
  int*    cur   = (int*)(ws + WS_CUR);
  int*    offs  = (int*)(ws + WS_OFF);
  int*    bsum  = (int*)(ws + WS_BSUM);
  int*    boff  = (int*)(ws + WS_BOFF);
  int*    elist = (int*)(ws + WS_ELIST);
  float4* posf  = (float4*)(ws + WS_POSF);
  u16*    wbws  = (u16*)(ws + WS_WB);

  (void)hipMemsetAsync(ws + WS_DEG, 0, 160000, stream);   // deg + cur

  k_sniff<<<1, 256, 0, stream>>>((const u32*)Wu, flag);
  k_prep<<<1, 256, 0, stream>>>(We, Wu, U3, U2, U1, w1g, w2g, w3g, w4g,
                                flag, Hws, U3ws, U2ws, U1ws, wbws);
  k_pos<<<79, 256, 0, stream>>>(pos, flag, posf);
  k_deg<<<1250, 256, 0, stream>>>(eidx, deg);
  k_scan_a<<<79, 256, 0, stream>>>(deg, bsum);
  k_scan_b<<<1, 128, 0, stream>>>(bsum, boff);
  k_scan_c<<<79, 256, 0, stream>>>(deg, boff, offs);
  k_scatter<<<1250, 256, 0, stream>>>(eidx, offs, cur, elist);
  k_main<<<5000, 256, 0, stream>>>(atom, eidx, Wc3, Wc2, Wc1, Wout,
                                   Hws, U3ws, U2ws, U1ws, posf, deg, offs, elist,
                                   wbws, flag, d_out);
}